// Round 1
// baseline (1098.962 us; speedup 1.0000x reference)
//
#include <hip/hip_runtime.h>

// MaxUnpooling2D: B=16, H=128, W=128, C=64, pool 2x2 -> OH=256, OW=256.
// out[b, y, x, f] += updates[b,h,w,f] where y = mask/(OW*C), x = (mask/C)%OW.
// Since OW*C = 16384 and C = 64 (powers of 2), and mask < OH*OW*C,
// out flat index within a batch = (mask & ~63) | (element's own channel).

constexpr int B = 16;
constexpr int H = 128;
constexpr int W = 128;
constexpr int C = 64;
constexpr int HWC   = H * W * C;        // 1<<20 per-batch input elements
constexpr int OHOWC = (2*H) * (2*W) * C; // 1<<22 per-batch output elements
constexpr int N = B * HWC;              // 16777216 total updates

__global__ __launch_bounds__(256) void unpool_scatter(
        const float4* __restrict__ upd4,
        const int4*   __restrict__ msk4,
        float*        __restrict__ out) {
    int i4 = blockIdx.x * blockDim.x + threadIdx.x;  // index in float4 units
    int i  = i4 << 2;                                // flat element index

    float4 u = upd4[i4];
    int4   m = msk4[i4];

    int b = i >> 20;          // i / HWC
    int f = i & 63;           // channel of first of the 4 elements
    float* outb = out + ((size_t)b << 22);  // b * OHOWC

    // idx = (mask & ~63) | channel   (channel = f..f+3, consecutive, f%4==0)
    atomicAdd(outb + ((m.x & ~63) | (f + 0)), u.x);
    atomicAdd(outb + ((m.y & ~63) | (f + 1)), u.y);
    atomicAdd(outb + ((m.z & ~63) | (f + 2)), u.z);
    atomicAdd(outb + ((m.w & ~63) | (f + 3)), u.w);
}

extern "C" void kernel_launch(void* const* d_in, const int* in_sizes, int n_in,
                              void* d_out, int out_size, void* d_ws, size_t ws_size,
                              hipStream_t stream) {
    const float* updates = (const float*)d_in[0];
    const int*   mask    = (const int*)d_in[1];
    float*       out     = (float*)d_out;

    // Zero-init output (harness re-poisons to 0xAA before every launch).
    hipMemsetAsync(out, 0, (size_t)out_size * sizeof(float), stream);

    constexpr int n4 = N / 4;            // 4194304 threads
    constexpr int blk = 256;
    unpool_scatter<<<n4 / blk, blk, 0, stream>>>(
        (const float4*)updates, (const int4*)mask, out);
}